// Round 1
// baseline (630.493 us; speedup 1.0000x reference)
//
#include <hip/hip_runtime.h>
#include <hip/hip_bf16.h>

// SpatialContextNet on MI355X (gfx950).
// Pipeline: invnorm -> corr partials (LDS stencil) -> reduce->bf16 At rows
// 1024..1055 -> transpose-cast feature -> At rows 0..1023 -> Wb cast ->
// bf16 MFMA GEMM (m97 structure) with fused bias+ReLU.
//
// Shapes: feature [8,1024,64,64] f32, conv_w [1024,1049] f32, conv_b [1024].
// Out [8,1024,64,64] f32. K padded 1049 -> 1056 (33 * BK32).

typedef __attribute__((ext_vector_type(8))) short short8x;
typedef __attribute__((ext_vector_type(4))) float floatx4;

#define B_   8
#define C_   1024
#define HW_  4096
#define KPAD 1056

// ---- bf16 helpers (bit-level, RNE) -----------------------------------------
__device__ __forceinline__ unsigned short f2bf(float f) {
  unsigned int u = __float_as_uint(f);
  u += 0x7FFFu + ((u >> 16) & 1u);
  return (unsigned short)(u >> 16);
}
__device__ __forceinline__ float bf2f(unsigned short s) {
  return __uint_as_float(((unsigned int)s) << 16);
}

// ---- async global->LDS 16B -------------------------------------------------
__device__ __forceinline__ void async16(const void* g, void* l) {
  __builtin_amdgcn_global_load_lds(
      (__attribute__((address_space(1))) void*)(void*)g,
      (__attribute__((address_space(3))) void*)l, 16, 0, 0);
}

// ---- K1a: partial sum of squares over 256-channel slices -------------------
// grid (16 mtiles, 4 csplit, 8 b), block 256. part[cs][b*4096+m]
__global__ __launch_bounds__(256) void scn_sumsq(const float* __restrict__ f,
                                                 float* __restrict__ part) {
  const int m  = blockIdx.x * 256 + threadIdx.x;
  const int cs = blockIdx.y, b = blockIdx.z;
  const float* p = f + ((size_t)b * C_ + cs * 256) * HW_ + m;
  float s = 0.f;
#pragma unroll 8
  for (int c = 0; c < 256; ++c) {
    float v = p[(size_t)c * HW_];
    s = fmaf(v, v, s);
  }
  part[(size_t)cs * (B_ * HW_) + b * HW_ + m] = s;
}

// ---- K1b: reduce 4 partials -> inv norm ------------------------------------
__global__ __launch_bounds__(256) void scn_invn(const float* __restrict__ part,
                                                float* __restrict__ invn) {
  const int i = blockIdx.x * 256 + threadIdx.x;  // b*4096+m, 32768 total
  float s = part[i] + part[32768 + i] + part[65536 + i] + part[98304 + i];
  invn[i] = 1.0f / fmaxf(sqrtf(s), 1e-12f);
}

// ---- K2a: correlation partials (raw feature products) ----------------------
// grid (4 tiles of 32x32, 16 csplit, 8 b), block 256 (8 ygroups x 32 x).
// Each thread: 4 y-positions, 25 accumulators each. 64 ch/block in 8 LDS
// passes of 8 ch. part layout: [cs][b][j][m] bf16, j = dx*5+dy.
__global__ __launch_bounds__(256) void scn_corr_part(
    const float* __restrict__ f, unsigned short* __restrict__ part) {
  __shared__ float lds[8][36][36];  // 41.5 KB
  const int tile = blockIdx.x;
  const int ty0 = (tile >> 1) * 32, tx0 = (tile & 1) * 32;
  const int cs = blockIdx.y, b = blockIdx.z;
  const int tid = threadIdx.x;
  const int xl = tid & 31;        // x within tile
  const int yb = (tid >> 5) * 4;  // y base within tile (4 rows per thread)

  float acc[25][4];
#pragma unroll
  for (int j = 0; j < 25; ++j)
#pragma unroll
    for (int p = 0; p < 4; ++p) acc[j][p] = 0.f;

#pragma unroll 1
  for (int pass = 0; pass < 8; ++pass) {
    __syncthreads();  // previous pass's reads done before overwrite
    const size_t cbase = ((size_t)b * C_ + cs * 64 + pass * 8) * HW_;
#pragma unroll 1
    for (int it = 0; it < 41; ++it) {
      int e = tid + it * 256;
      if (e < 10368) {  // 8 * 36 * 36
        int ch = e / 1296;
        int rem = e - ch * 1296;
        int yy = rem / 36;
        int xx = rem - yy * 36;
        int gy = ty0 + yy - 2, gx = tx0 + xx - 2;
        float v = 0.f;
        if (gy >= 0 && gy < 64 && gx >= 0 && gx < 64)
          v = f[cbase + (size_t)ch * HW_ + gy * 64 + gx];
        lds[ch][yy][xx] = v;
      }
    }
    __syncthreads();
#pragma unroll 1
    for (int ch = 0; ch < 8; ++ch) {
      float ctr[4];
#pragma unroll
      for (int p = 0; p < 4; ++p) ctr[p] = lds[ch][yb + p + 2][xl + 2];
#pragma unroll
      for (int dx = 0; dx < 5; ++dx) {
        float col[8];
#pragma unroll
        for (int q = 0; q < 8; ++q) col[q] = lds[ch][yb + q][xl + dx];
#pragma unroll
        for (int dy = 0; dy < 5; ++dy)
#pragma unroll
          for (int p = 0; p < 4; ++p)
            acc[dx * 5 + dy][p] = fmaf(col[p + dy], ctr[p], acc[dx * 5 + dy][p]);
      }
    }
  }
  // write partials
  const int x = tx0 + xl;
#pragma unroll 1
  for (int j = 0; j < 25; ++j) {
#pragma unroll
    for (int p = 0; p < 4; ++p) {
      int y = ty0 + yb + p;
      part[(((size_t)cs * B_ + b) * 25 + j) * HW_ + y * 64 + x] = f2bf(acc[j][p]);
    }
  }
}

// ---- K2b: reduce partials, apply norms, write At rows 1024..1055 -----------
// grid 128, block 256 (one thread per (b,m)).
__global__ __launch_bounds__(256) void scn_corr_reduce(
    const unsigned short* __restrict__ part, const float* __restrict__ invn,
    unsigned short* __restrict__ At) {
  const int i = blockIdx.x * 256 + threadIdx.x;  // b*4096+m
  const int b = i >> 12, m = i & 4095;
  const int y = m >> 6, x = m & 63;
  const float ic = invn[i];
  unsigned short* row = At + ((size_t)b * HW_ + m) * KPAD + 1024;
#pragma unroll 1
  for (int j = 0; j < 25; ++j) {
    const int dy = (j % 5) - 2, dx = (j / 5) - 2;
    float s = 0.f;
#pragma unroll
    for (int cs = 0; cs < 16; ++cs)
      s += bf2f(part[(((size_t)cs * B_ + b) * 25 + j) * HW_ + m]);
    const int ny = y + dy, nx = x + dx;
    float in2 = (ny >= 0 && ny < 64 && nx >= 0 && nx < 64)
                    ? invn[(b << 12) + (ny << 6) + nx] : 0.f;
    row[j] = f2bf(s * ic * in2);
  }
#pragma unroll
  for (int j = 25; j < 32; ++j) row[j] = 0;  // zero K-pad 1049..1055
}

// ---- K3: transpose-cast feature [b][k][m] -> At [b][m][k] bf16 -------------
// grid (64 mtiles, 16 ktiles, 8 b), block 256; 64x64 tiles.
__global__ __launch_bounds__(256) void scn_transpose(
    const float* __restrict__ f, unsigned short* __restrict__ At) {
  __shared__ float lds[64][65];
  const int mt = blockIdx.x, kt = blockIdx.y, b = blockIdx.z;
  const int tid = threadIdx.x;
  const float* src = f + ((size_t)b * C_ + kt * 64) * HW_ + mt * 64;
  const int mi = tid & 63, kr = tid >> 6;
#pragma unroll
  for (int i = 0; i < 16; ++i)
    lds[kr + i * 4][mi] = src[(size_t)(kr + i * 4) * HW_ + mi];
  __syncthreads();
  unsigned short* dst = At + ((size_t)b * HW_ + mt * 64) * KPAD + kt * 64;
  const int c = tid & 7, mr = tid >> 3;  // 8 k-chunks x 32 m-rows
#pragma unroll
  for (int half = 0; half < 2; ++half) {
    const int mm = mr + half * 32;
    short8x v;
#pragma unroll
    for (int j = 0; j < 8; ++j) v[j] = (short)f2bf(lds[c * 8 + j][mm]);
    *(short8x*)(dst + (size_t)mm * KPAD + c * 8) = v;
  }
}

// ---- K4: cast+pad conv_w -> Wb [1024][1056] bf16 ---------------------------
__global__ __launch_bounds__(256) void scn_wcast(const float* __restrict__ w,
                                                 unsigned short* __restrict__ Wb) {
  const int i = blockIdx.x * 256 + threadIdx.x;  // 1024*1056
  const int o = i / KPAD, k = i - o * KPAD;
  Wb[i] = (k < 1049) ? f2bf(w[(size_t)o * 1049 + k]) : 0;
}

// ---- K5: bf16 MFMA GEMM + bias + ReLU --------------------------------------
// C[o,m] = W[o,:] . At[m,:], per batch. 128x128 tile, BK=32, 4 waves 2x2,
// each wave 4x4 of 16x16x32 MFMA. global_load_lds 16B staging (m97 structure).
__global__ __launch_bounds__(256) void scn_gemm(
    const unsigned short* __restrict__ Wb, const unsigned short* __restrict__ At,
    const float* __restrict__ bias, float* __restrict__ out) {
  __shared__ __align__(16) unsigned short lA[128 * 32];  // W tile   [row][k]
  __shared__ __align__(16) unsigned short lB[128 * 32];  // At tile  [row][k]
  const int tid = threadIdx.x;
  const int nb = blockIdx.x, ob = blockIdx.y, b = blockIdx.z;

  // staging: thread t -> row t/4 (+64 for second half), k-chunk (t%4)*8
  const int srow = tid >> 2;
  const int skc = (tid & 3) * 8;
  const unsigned short* gW0 = Wb + (size_t)(ob * 128 + srow) * KPAD + skc;
  const unsigned short* gW1 = gW0 + (size_t)64 * KPAD;
  const unsigned short* gB0 = At + ((size_t)b * HW_ + nb * 128 + srow) * KPAD + skc;
  const unsigned short* gB1 = gB0 + (size_t)64 * KPAD;
  char* dA0 = (char*)lA + tid * 16;
  char* dA1 = (char*)lA + 4096 + tid * 16;
  char* dB0 = (char*)lB + tid * 16;
  char* dB1 = (char*)lB + 4096 + tid * 16;

  const int w = tid >> 6, l = tid & 63;
  const int wm = (w & 1) << 6, wn = (w >> 1) << 6;
  const int l16 = l & 15, l4 = l >> 4;
  const unsigned short* rA = lA + (wm + l16) * 32 + l4 * 8;
  const unsigned short* rB = lB + (wn + l16) * 32 + l4 * 8;

  floatx4 acc[4][4];
#pragma unroll
  for (int i = 0; i < 4; ++i)
#pragma unroll
    for (int j = 0; j < 4; ++j) acc[i][j] = (floatx4){0.f, 0.f, 0.f, 0.f};

  for (int kt = 0; kt < 33; ++kt) {
    const int ko = kt * 32;
    async16(gW0 + ko, dA0);
    async16(gW1 + ko, dA1);
    async16(gB0 + ko, dB0);
    async16(gB1 + ko, dB1);
    __syncthreads();  // drains vmcnt (global_load_lds) for all waves
    short8x a[4], bb[4];
#pragma unroll
    for (int i = 0; i < 4; ++i) a[i] = *(const short8x*)(rA + i * 16 * 32);
#pragma unroll
    for (int j = 0; j < 4; ++j) bb[j] = *(const short8x*)(rB + j * 16 * 32);
#pragma unroll
    for (int i = 0; i < 4; ++i)
#pragma unroll
      for (int j = 0; j < 4; ++j)
        acc[i][j] =
            __builtin_amdgcn_mfma_f32_16x16x32_bf16(a[i], bb[j], acc[i][j], 0, 0, 0);
    __syncthreads();  // LDS reads done before next staging overwrites
  }

  // epilogue: C/D layout col=lane&15 (m), row=(lane>>4)*4+r (o)
  float* outb = out + (size_t)b * C_ * HW_;
#pragma unroll
  for (int i = 0; i < 4; ++i) {
    const int o0 = ob * 128 + wm + i * 16 + l4 * 4;
    float bs[4];
#pragma unroll
    for (int r = 0; r < 4; ++r) bs[r] = bias[o0 + r];
#pragma unroll
    for (int j = 0; j < 4; ++j) {
      const int m = nb * 128 + wn + j * 16 + l16;
#pragma unroll
      for (int r = 0; r < 4; ++r) {
        float v = acc[i][j][r] + bs[r];
        outb[(size_t)(o0 + r) * HW_ + m] = v > 0.f ? v : 0.f;
      }
    }
  }
}

// ---- launch ----------------------------------------------------------------
extern "C" void kernel_launch(void* const* d_in, const int* in_sizes, int n_in,
                              void* d_out, int out_size, void* d_ws, size_t ws_size,
                              hipStream_t stream) {
  const float* feature = (const float*)d_in[0];
  const float* conv_w  = (const float*)d_in[1];
  const float* conv_b  = (const float*)d_in[2];
  float* out = (float*)d_out;

  // workspace layout (bytes): total ~98.3 MB
  char* ws = (char*)d_ws;
  float* invn            = (float*)(ws);                    // 131072
  float* sumsqp          = (float*)(ws + 131072);           // 524288
  unsigned short* corrp  = (unsigned short*)(ws + 655360);  // 26214400
  unsigned short* Wb     = (unsigned short*)(ws + 26869760);// 2162688
  unsigned short* At     = (unsigned short*)(ws + 29032448);// 69206016

  scn_sumsq<<<dim3(16, 4, 8), 256, 0, stream>>>(feature, sumsqp);
  scn_invn<<<dim3(128), 256, 0, stream>>>(sumsqp, invn);
  scn_corr_part<<<dim3(4, 16, 8), 256, 0, stream>>>(feature, corrp);
  scn_corr_reduce<<<dim3(128), 256, 0, stream>>>(corrp, invn, At);
  scn_transpose<<<dim3(64, 16, 8), 256, 0, stream>>>(feature, At);
  scn_wcast<<<dim3((1024 * KPAD) / 256), 256, 0, stream>>>(conv_w, Wb);
  scn_gemm<<<dim3(32, 8, 8), 256, 0, stream>>>(Wb, At, conv_b, out);
}

// Round 2
// 586.003 us; speedup vs baseline: 1.0759x; 1.0759x over previous
//
#include <hip/hip_runtime.h>
#include <hip/hip_bf16.h>

// SpatialContextNet on MI355X (gfx950). Round 2.
// Order: memset(sumsq) -> corr_part (cold feature read, dense block-local
// partials) -> transpose+sumsq fused (L3-warm feature) -> invn ->
// corr_reduce (norms applied, At rows 1024..1055) -> wcast -> MFMA GEMM.
//
// feature [8,1024,64,64] f32, conv_w [1024,1049] f32, conv_b [1024] f32.
// Out [8,1024,64,64] f32. K padded 1049 -> 1056.

typedef __attribute__((ext_vector_type(8))) short short8x;
typedef __attribute__((ext_vector_type(4))) float floatx4;

#define B_   8
#define C_   1024
#define HW_  4096
#define KPAD 1056

__device__ __forceinline__ unsigned short f2bf(float f) {
  unsigned int u = __float_as_uint(f);
  u += 0x7FFFu + ((u >> 16) & 1u);
  return (unsigned short)(u >> 16);
}
__device__ __forceinline__ float bf2f(unsigned short s) {
  return __uint_as_float(((unsigned int)s) << 16);
}

__device__ __forceinline__ void async16(const void* g, void* l) {
  __builtin_amdgcn_global_load_lds(
      (__attribute__((address_space(1))) void*)(void*)g,
      (__attribute__((address_space(3))) void*)l, 16, 0, 0);
}

// ---- K1: correlation partials, block-contiguous dense layout ---------------
// grid (8 tiles of 16x32, 16 cs, 8 b), block 256. 2 px/thread, 8 passes x 8ch.
// part[((cs*8+b)*8 + tile)*25*512 + j*512 + (p*256+tid)]  (bf16)
__global__ __launch_bounds__(256) void scn_corr_part(
    const float* __restrict__ f, unsigned short* __restrict__ part) {
  __shared__ float lds[8][20][36];  // 23040 B
  const int tile = blockIdx.x;
  const int ty0 = (tile >> 1) * 16, tx0 = (tile & 1) * 32;
  const int cs = blockIdx.y, b = blockIdx.z;
  const int tid = threadIdx.x;
  const int xl = tid & 31;   // x within tile
  const int yg = tid >> 5;   // y pair index (rows yg*2, yg*2+1)

  float acc[25][2];
#pragma unroll
  for (int j = 0; j < 25; ++j) { acc[j][0] = 0.f; acc[j][1] = 0.f; }

  const int fch = tid >> 5, lane = tid & 31;

#pragma unroll 1
  for (int pass = 0; pass < 8; ++pass) {
    __syncthreads();  // protect previous pass's reads
    const size_t cbase = ((size_t)b * C_ + cs * 64 + pass * 8) * HW_;
    // fill: 8 ch x 20 x 36 = 5760 elems; per ch 720, 32 lanes x 23 iters
#pragma unroll
    for (int it = 0; it < 23; ++it) {
      int e = lane + it * 32;
      if (e < 720) {
        int yy = e / 36;
        int xx = e - yy * 36;
        int gy = ty0 + yy - 2, gx = tx0 + xx - 2;
        float v = 0.f;
        if (gy >= 0 && gy < 64 && gx >= 0 && gx < 64)
          v = f[cbase + (size_t)fch * HW_ + gy * 64 + gx];
        lds[fch][yy][xx] = v;
      }
    }
    __syncthreads();
#pragma unroll 1
    for (int ch = 0; ch < 8; ++ch) {
      const float ctr0 = lds[ch][yg * 2 + 2][xl + 2];
      const float ctr1 = lds[ch][yg * 2 + 3][xl + 2];
#pragma unroll
      for (int dx = 0; dx < 5; ++dx) {
        float col[6];
#pragma unroll
        for (int q = 0; q < 6; ++q) col[q] = lds[ch][yg * 2 + q][xl + dx];
#pragma unroll
        for (int dy = 0; dy < 5; ++dy) {
          acc[dx * 5 + dy][0] = fmaf(col[dy], ctr0, acc[dx * 5 + dy][0]);
          acc[dx * 5 + dy][1] = fmaf(col[dy + 1], ctr1, acc[dx * 5 + dy][1]);
        }
      }
    }
  }
  unsigned short* pb = part + (size_t)(((cs * 8 + b) * 8 + tile) * 25) * 512;
#pragma unroll
  for (int j = 0; j < 25; ++j) {
    pb[j * 512 + tid]       = f2bf(acc[j][0]);
    pb[j * 512 + 256 + tid] = f2bf(acc[j][1]);
  }
}

// ---- K2: transpose-cast feature -> At rows 0..1023, fused sumsq ------------
// grid (64 mtiles, 16 ktiles, 8 b), block 256; 64x64 tiles.
__global__ __launch_bounds__(256) void scn_transpose(
    const float* __restrict__ f, unsigned short* __restrict__ At,
    float* __restrict__ sumsq) {
  __shared__ float lds[64][65];
  const int mt = blockIdx.x, kt = blockIdx.y, b = blockIdx.z;
  const int tid = threadIdx.x;
  const float* src = f + ((size_t)b * C_ + kt * 64) * HW_ + mt * 64;
  const int mi = tid & 63, kr = tid >> 6;
  float s = 0.f;
#pragma unroll
  for (int i = 0; i < 16; ++i) {
    float v = src[(size_t)(kr + i * 4) * HW_ + mi];
    lds[kr + i * 4][mi] = v;
    s = fmaf(v, v, s);
  }
  atomicAdd(&sumsq[b * HW_ + mt * 64 + mi], s);
  __syncthreads();
  unsigned short* dst = At + ((size_t)b * HW_ + mt * 64) * KPAD + kt * 64;
  const int c = tid & 7, mr = tid >> 3;
#pragma unroll
  for (int half = 0; half < 2; ++half) {
    const int mm = mr + half * 32;
    short8x v;
#pragma unroll
    for (int j = 0; j < 8; ++j) v[j] = (short)f2bf(lds[c * 8 + j][mm]);
    *(short8x*)(dst + (size_t)mm * KPAD + c * 8) = v;
  }
}

// ---- K3: inv norm ----------------------------------------------------------
__global__ __launch_bounds__(256) void scn_invn(const float* __restrict__ sumsq,
                                                float* __restrict__ invn) {
  const int i = blockIdx.x * 256 + threadIdx.x;
  invn[i] = 1.0f / fmaxf(sqrtf(sumsq[i]), 1e-12f);
}

// ---- K4: reduce partials over cs, apply norms, write At rows 1024..1055 ----
// grid (16 mchunks, 8 b), block 256 (one thread per (b,m)).
__global__ __launch_bounds__(256) void scn_corr_reduce(
    const unsigned short* __restrict__ part, const float* __restrict__ invn,
    unsigned short* __restrict__ At) {
  const int b = blockIdx.y;
  const int m = blockIdx.x * 256 + threadIdx.x;
  const int y = m >> 6, x = m & 63;
  const int tile = ((y >> 4) << 1) | (x >> 5);
  const int yl = y & 15, xl = x & 31;
  const int px = ((yl & 1) << 8) | ((yl >> 1) << 5) | xl;  // p*256 + tid

  float acc[25];
#pragma unroll
  for (int j = 0; j < 25; ++j) acc[j] = 0.f;
#pragma unroll 1
  for (int cs = 0; cs < 16; ++cs) {
    const unsigned short* pb =
        part + (size_t)(((cs * 8 + b) * 8 + tile) * 25) * 512 + px;
#pragma unroll
    for (int j = 0; j < 25; ++j) acc[j] += bf2f(pb[j * 512]);
  }
  const float ic = invn[b * HW_ + m];
  unsigned short r[32];
#pragma unroll
  for (int j = 0; j < 25; ++j) {
    const int dy = (j % 5) - 2, dx = (j / 5) - 2;
    const int ny = y + dy, nx = x + dx;
    float in2 = (ny >= 0 && ny < 64 && nx >= 0 && nx < 64)
                    ? invn[b * HW_ + (ny << 6) + nx] : 0.f;
    r[j] = f2bf(acc[j] * ic * in2);
  }
#pragma unroll
  for (int j = 25; j < 32; ++j) r[j] = 0;
  unsigned short* row = At + ((size_t)b * HW_ + m) * KPAD + 1024;
#pragma unroll
  for (int v = 0; v < 4; ++v) *(short8x*)(row + v * 8) = *(short8x*)(r + v * 8);
}

// ---- K5: cast+pad conv_w -> Wb [1024][1056] bf16 ---------------------------
__global__ __launch_bounds__(256) void scn_wcast(const float* __restrict__ w,
                                                 unsigned short* __restrict__ Wb) {
  const int i = blockIdx.x * 256 + threadIdx.x;
  const int o = i / KPAD, k = i - o * KPAD;
  Wb[i] = (k < 1049) ? f2bf(w[(size_t)o * 1049 + k]) : 0;
}

// ---- K6: bf16 MFMA GEMM + bias + ReLU (m97 structure) ----------------------
__global__ __launch_bounds__(256) void scn_gemm(
    const unsigned short* __restrict__ Wb, const unsigned short* __restrict__ At,
    const float* __restrict__ bias, float* __restrict__ out) {
  __shared__ __align__(16) unsigned short lA[128 * 32];
  __shared__ __align__(16) unsigned short lB[128 * 32];
  const int tid = threadIdx.x;
  const int nb = blockIdx.x, ob = blockIdx.y, b = blockIdx.z;

  const int srow = tid >> 2;
  const int skc = (tid & 3) * 8;
  const unsigned short* gW0 = Wb + (size_t)(ob * 128 + srow) * KPAD + skc;
  const unsigned short* gW1 = gW0 + (size_t)64 * KPAD;
  const unsigned short* gB0 = At + ((size_t)b * HW_ + nb * 128 + srow) * KPAD + skc;
  const unsigned short* gB1 = gB0 + (size_t)64 * KPAD;
  char* dA0 = (char*)lA + tid * 16;
  char* dA1 = (char*)lA + 4096 + tid * 16;
  char* dB0 = (char*)lB + tid * 16;
  char* dB1 = (char*)lB + 4096 + tid * 16;

  const int w = tid >> 6, l = tid & 63;
  const int wm = (w & 1) << 6, wn = (w >> 1) << 6;
  const int l16 = l & 15, l4 = l >> 4;
  const unsigned short* rA = lA + (wm + l16) * 32 + l4 * 8;
  const unsigned short* rB = lB + (wn + l16) * 32 + l4 * 8;

  floatx4 acc[4][4];
#pragma unroll
  for (int i = 0; i < 4; ++i)
#pragma unroll
    for (int j = 0; j < 4; ++j) acc[i][j] = (floatx4){0.f, 0.f, 0.f, 0.f};

  for (int kt = 0; kt < 33; ++kt) {
    const int ko = kt * 32;
    async16(gW0 + ko, dA0);
    async16(gW1 + ko, dA1);
    async16(gB0 + ko, dB0);
    async16(gB1 + ko, dB1);
    __syncthreads();
    short8x a[4], bb[4];
#pragma unroll
    for (int i = 0; i < 4; ++i) a[i] = *(const short8x*)(rA + i * 16 * 32);
#pragma unroll
    for (int j = 0; j < 4; ++j) bb[j] = *(const short8x*)(rB + j * 16 * 32);
#pragma unroll
    for (int i = 0; i < 4; ++i)
#pragma unroll
      for (int j = 0; j < 4; ++j)
        acc[i][j] =
            __builtin_amdgcn_mfma_f32_16x16x32_bf16(a[i], bb[j], acc[i][j], 0, 0, 0);
    __syncthreads();
  }

  float* outb = out + (size_t)b * C_ * HW_;
#pragma unroll
  for (int i = 0; i < 4; ++i) {
    const int o0 = ob * 128 + wm + i * 16 + l4 * 4;
    float bs[4];
#pragma unroll
    for (int r = 0; r < 4; ++r) bs[r] = bias[o0 + r];
#pragma unroll
    for (int j = 0; j < 4; ++j) {
      const int m = nb * 128 + wn + j * 16 + l16;
#pragma unroll
      for (int r = 0; r < 4; ++r) {
        float v = acc[i][j][r] + bs[r];
        outb[(size_t)(o0 + r) * HW_ + m] = v > 0.f ? v : 0.f;
      }
    }
  }
}

// ---- launch ----------------------------------------------------------------
extern "C" void kernel_launch(void* const* d_in, const int* in_sizes, int n_in,
                              void* d_out, int out_size, void* d_ws, size_t ws_size,
                              hipStream_t stream) {
  const float* feature = (const float*)d_in[0];
  const float* conv_w  = (const float*)d_in[1];
  const float* conv_b  = (const float*)d_in[2];
  float* out = (float*)d_out;

  // workspace layout (bytes), total 97,845,248 (< 98.3 MB known-good)
  char* ws = (char*)d_ws;
  unsigned short* At    = (unsigned short*)(ws);              // 69,206,016
  unsigned short* part  = (unsigned short*)(ws + 69206016);   // 26,214,400
  unsigned short* Wb    = (unsigned short*)(ws + 95420416);   //  2,162,688
  float* invn           = (float*)(ws + 97583104);            //    131,072
  float* sumsq          = (float*)(ws + 97714176);            //    131,072

  hipMemsetAsync(sumsq, 0, 131072, stream);
  scn_corr_part<<<dim3(8, 16, 8), 256, 0, stream>>>(feature, part);
  scn_transpose<<<dim3(64, 16, 8), 256, 0, stream>>>(feature, At, sumsq);
  scn_invn<<<dim3(128), 256, 0, stream>>>(sumsq, invn);
  scn_corr_reduce<<<dim3(16, 8), 256, 0, stream>>>(part, invn, At);
  scn_wcast<<<dim3((1024 * KPAD) / 256), 256, 0, stream>>>(conv_w, Wb);
  scn_gemm<<<dim3(32, 8, 8), 256, 0, stream>>>(Wb, At, conv_b, out);
}

// Round 3
// 444.129 us; speedup vs baseline: 1.4196x; 1.3194x over previous
//
#include <hip/hip_runtime.h>
#include <hip/hip_bf16.h>

// SpatialContextNet on MI355X (gfx950). Round 3.
// corr_part rewritten: wave-per-row, LDS-free, barrier-free. Uses the
// shift-hoist identity corr_j(y,x-dx) = [Sum_c f[y+dy][x] * f[y][x-dx]] * norms,
// realized as a rotated coalesced store. j=12 partial doubles as sumsq.
//
// feature [8,1024,64,64] f32, conv_w [1024,1049] f32, conv_b [1024] f32.
// Out [8,1024,64,64] f32. K padded 1049 -> 1056.

typedef __attribute__((ext_vector_type(8))) short short8x;
typedef __attribute__((ext_vector_type(4))) float floatx4;

#define B_   8
#define C_   1024
#define HW_  4096
#define KPAD 1056

__device__ __forceinline__ unsigned short f2bf(float f) {
  unsigned int u = __float_as_uint(f);
  u += 0x7FFFu + ((u >> 16) & 1u);
  return (unsigned short)(u >> 16);
}
__device__ __forceinline__ float bf2f(unsigned short s) {
  return __uint_as_float(((unsigned int)s) << 16);
}

__device__ __forceinline__ void async16(const void* g, void* l) {
  __builtin_amdgcn_global_load_lds(
      (__attribute__((address_space(1))) void*)(void*)g,
      (__attribute__((address_space(3))) void*)l, 16, 0, 0);
}

// ---- K1: correlation partials, wave-per-row, no LDS ------------------------
// grid (8 ystrips, 8 cs, 8 b), block 512 (8 waves = 8 rows).
// part[(cs*25+j)*32768 + b*4096 + y*64 + x]  (f32)
// h_j(x) = Sum_c f[y+dy][x] * f[y][x-dx]; stored rotated so slot (y,x) holds
// corr-partial for output pixel (y,x) = Sum_c f[y+dy][x+dx]*f[y][x].
__global__ __launch_bounds__(512) void scn_corr_part(
    const float* __restrict__ f, float* __restrict__ part) {
  const int tid = threadIdx.x;
  const int x = tid & 63;
  const int y = blockIdx.x * 8 + (tid >> 6);
  const int cs = blockIdx.y, b = blockIdx.z;

  // clamped shifted-center x indices; OOB lanes produce garbage h that the
  // rotated store discards (their target pixel is out of the row).
  const int xs0 = (x + 2 < 64) ? x + 2 : 63;  // c(x-dx) for dx=-2
  const int xs1 = (x + 1 < 64) ? x + 1 : 63;  // dx=-1
  const int xs3 = (x - 1 >= 0) ? x - 1 : 0;   // dx=+1
  const int xs4 = (x - 2 >= 0) ? x - 2 : 0;   // dx=+2

  const bool ym2 = (y >= 2), ym1 = (y >= 1), yp1 = (y <= 62), yp2 = (y <= 61);

  const float* rp0 = f + ((size_t)b * C_ + cs * 128) * HW_ + y * 64;

  float h[25];
#pragma unroll
  for (int j = 0; j < 25; ++j) h[j] = 0.f;

#pragma unroll 4
  for (int c = 0; c < 128; ++c) {
    const float* rp = rp0 + (size_t)c * HW_;
    const float ctr = rp[x];
    const float vm2 = ym2 ? rp[x - 128] : 0.f;
    const float vm1 = ym1 ? rp[x - 64] : 0.f;
    const float vp1 = yp1 ? rp[x + 64] : 0.f;
    const float vp2 = yp2 ? rp[x + 128] : 0.f;
    const float c0 = rp[xs0], c1 = rp[xs1], c3 = rp[xs3], c4 = rp[xs4];
    const float v[5] = {vm2, vm1, ctr, vp1, vp2};
    const float cc[5] = {c0, c1, ctr, c3, c4};
#pragma unroll
    for (int dxi = 0; dxi < 5; ++dxi)
#pragma unroll
      for (int dyi = 0; dyi < 5; ++dyi)
        h[dxi * 5 + dyi] = fmaf(v[dyi], cc[dxi], h[dxi * 5 + dyi]);
  }

  float* pb = part + (size_t)(cs * 25) * 32768 + b * HW_ + y * 64;
#pragma unroll
  for (int j = 0; j < 25; ++j) {
    const int dx = (j / 5) - 2;
    const int tgt = x - dx;
    const int wx = (tgt + 64) & 63;
    const float val = ((unsigned)tgt < 64u) ? h[j] : 0.f;
    pb[(size_t)j * 32768 + wx] = val;
  }
}

// ---- K2: transpose-cast feature [b][k][m] -> At [b][m][k] bf16 -------------
// grid (64 mtiles, 16 ktiles, 8 b), block 256; 64x64 tiles.
__global__ __launch_bounds__(256) void scn_transpose(
    const float* __restrict__ f, unsigned short* __restrict__ At) {
  __shared__ float lds[64][65];
  const int mt = blockIdx.x, kt = blockIdx.y, b = blockIdx.z;
  const int tid = threadIdx.x;
  const float* src = f + ((size_t)b * C_ + kt * 64) * HW_ + mt * 64;
  const int mi = tid & 63, kr = tid >> 6;
#pragma unroll
  for (int i = 0; i < 16; ++i)
    lds[kr + i * 4][mi] = src[(size_t)(kr + i * 4) * HW_ + mi];
  __syncthreads();
  unsigned short* dst = At + ((size_t)b * HW_ + mt * 64) * KPAD + kt * 64;
  const int c = tid & 7, mr = tid >> 3;
#pragma unroll
  for (int half = 0; half < 2; ++half) {
    const int mm = mr + half * 32;
    short8x v;
#pragma unroll
    for (int j = 0; j < 8; ++j) v[j] = (short)f2bf(lds[c * 8 + j][mm]);
    *(short8x*)(dst + (size_t)mm * KPAD + c * 8) = v;
  }
}

// ---- K3: inv norm from j=12 partial slices ---------------------------------
__global__ __launch_bounds__(256) void scn_invn(const float* __restrict__ part,
                                                float* __restrict__ invn) {
  const int i = blockIdx.x * 256 + threadIdx.x;  // b*4096+m, 32768 total
  float s = 0.f;
#pragma unroll
  for (int cs = 0; cs < 8; ++cs) s += part[(size_t)(cs * 25 + 12) * 32768 + i];
  invn[i] = 1.0f / fmaxf(sqrtf(s), 1e-12f);
}

// ---- K4: reduce partials over cs, apply norms, write At rows 1024..1055 ----
// grid (16, 8), block 256 (one thread per (b,m)).
__global__ __launch_bounds__(256) void scn_corr_reduce(
    const float* __restrict__ part, const float* __restrict__ invn,
    unsigned short* __restrict__ At) {
  const int b = blockIdx.y;
  const int m = blockIdx.x * 256 + threadIdx.x;
  const int i = b * HW_ + m;
  const int y = m >> 6, x = m & 63;

  float acc[25];
#pragma unroll
  for (int j = 0; j < 25; ++j) acc[j] = 0.f;
#pragma unroll 1
  for (int cs = 0; cs < 8; ++cs) {
    const float* pb = part + (size_t)(cs * 25) * 32768 + i;
#pragma unroll
    for (int j = 0; j < 25; ++j) acc[j] += pb[(size_t)j * 32768];
  }
  const float ic = invn[i];
  unsigned short r[32];
#pragma unroll
  for (int j = 0; j < 25; ++j) {
    const int dy = (j % 5) - 2, dx = (j / 5) - 2;
    const int ny = y + dy, nx = x + dx;
    float in2 = (ny >= 0 && ny < 64 && nx >= 0 && nx < 64)
                    ? invn[b * HW_ + (ny << 6) + nx] : 0.f;
    r[j] = f2bf(acc[j] * ic * in2);
  }
#pragma unroll
  for (int j = 25; j < 32; ++j) r[j] = 0;
  unsigned short* row = At + ((size_t)b * HW_ + m) * KPAD + 1024;
#pragma unroll
  for (int v = 0; v < 4; ++v) *(short8x*)(row + v * 8) = *(short8x*)(r + v * 8);
}

// ---- K5: cast+pad conv_w -> Wb [1024][1056] bf16 ---------------------------
__global__ __launch_bounds__(256) void scn_wcast(const float* __restrict__ w,
                                                 unsigned short* __restrict__ Wb) {
  const int i = blockIdx.x * 256 + threadIdx.x;
  const int o = i / KPAD, k = i - o * KPAD;
  Wb[i] = (k < 1049) ? f2bf(w[(size_t)o * 1049 + k]) : 0;
}

// ---- K6: bf16 MFMA GEMM + bias + ReLU (m97 structure) ----------------------
__global__ __launch_bounds__(256) void scn_gemm(
    const unsigned short* __restrict__ Wb, const unsigned short* __restrict__ At,
    const float* __restrict__ bias, float* __restrict__ out) {
  __shared__ __align__(16) unsigned short lA[128 * 32];
  __shared__ __align__(16) unsigned short lB[128 * 32];
  const int tid = threadIdx.x;
  const int nb = blockIdx.x, ob = blockIdx.y, b = blockIdx.z;

  const int srow = tid >> 2;
  const int skc = (tid & 3) * 8;
  const unsigned short* gW0 = Wb + (size_t)(ob * 128 + srow) * KPAD + skc;
  const unsigned short* gW1 = gW0 + (size_t)64 * KPAD;
  const unsigned short* gB0 = At + ((size_t)b * HW_ + nb * 128 + srow) * KPAD + skc;
  const unsigned short* gB1 = gB0 + (size_t)64 * KPAD;
  char* dA0 = (char*)lA + tid * 16;
  char* dA1 = (char*)lA + 4096 + tid * 16;
  char* dB0 = (char*)lB + tid * 16;
  char* dB1 = (char*)lB + 4096 + tid * 16;

  const int w = tid >> 6, l = tid & 63;
  const int wm = (w & 1) << 6, wn = (w >> 1) << 6;
  const int l16 = l & 15, l4 = l >> 4;
  const unsigned short* rA = lA + (wm + l16) * 32 + l4 * 8;
  const unsigned short* rB = lB + (wn + l16) * 32 + l4 * 8;

  floatx4 acc[4][4];
#pragma unroll
  for (int i = 0; i < 4; ++i)
#pragma unroll
    for (int j = 0; j < 4; ++j) acc[i][j] = (floatx4){0.f, 0.f, 0.f, 0.f};

  for (int kt = 0; kt < 33; ++kt) {
    const int ko = kt * 32;
    async16(gW0 + ko, dA0);
    async16(gW1 + ko, dA1);
    async16(gB0 + ko, dB0);
    async16(gB1 + ko, dB1);
    __syncthreads();
    short8x a[4], bb[4];
#pragma unroll
    for (int i = 0; i < 4; ++i) a[i] = *(const short8x*)(rA + i * 16 * 32);
#pragma unroll
    for (int j = 0; j < 4; ++j) bb[j] = *(const short8x*)(rB + j * 16 * 32);
#pragma unroll
    for (int i = 0; i < 4; ++i)
#pragma unroll
      for (int j = 0; j < 4; ++j)
        acc[i][j] =
            __builtin_amdgcn_mfma_f32_16x16x32_bf16(a[i], bb[j], acc[i][j], 0, 0, 0);
    __syncthreads();
  }

  float* outb = out + (size_t)b * C_ * HW_;
#pragma unroll
  for (int i = 0; i < 4; ++i) {
    const int o0 = ob * 128 + wm + i * 16 + l4 * 4;
    float bs[4];
#pragma unroll
    for (int r = 0; r < 4; ++r) bs[r] = bias[o0 + r];
#pragma unroll
    for (int j = 0; j < 4; ++j) {
      const int m = nb * 128 + wn + j * 16 + l16;
#pragma unroll
      for (int r = 0; r < 4; ++r) {
        float v = acc[i][j][r] + bs[r];
        outb[(size_t)(o0 + r) * HW_ + m] = v > 0.f ? v : 0.f;
      }
    }
  }
}

// ---- launch ----------------------------------------------------------------
extern "C" void kernel_launch(void* const* d_in, const int* in_sizes, int n_in,
                              void* d_out, int out_size, void* d_ws, size_t ws_size,
                              hipStream_t stream) {
  const float* feature = (const float*)d_in[0];
  const float* conv_w  = (const float*)d_in[1];
  const float* conv_b  = (const float*)d_in[2];
  float* out = (float*)d_out;

  // workspace layout (bytes), total 97,714,176
  char* ws = (char*)d_ws;
  unsigned short* At = (unsigned short*)(ws);             // 69,206,016
  float* part        = (float*)(ws + 69206016);           // 26,214,400
  unsigned short* Wb = (unsigned short*)(ws + 95420416);  //  2,162,688
  float* invn        = (float*)(ws + 97583104);           //    131,072

  scn_corr_part<<<dim3(8, 8, 8), 512, 0, stream>>>(feature, part);
  scn_transpose<<<dim3(64, 16, 8), 256, 0, stream>>>(feature, At);
  scn_invn<<<dim3(128), 256, 0, stream>>>(part, invn);
  scn_corr_reduce<<<dim3(16, 8), 256, 0, stream>>>(part, invn, At);
  scn_wcast<<<dim3((1024 * KPAD) / 256), 256, 0, stream>>>(conv_w, Wb);
  scn_gemm<<<dim3(32, 8, 8), 256, 0, stream>>>(Wb, At, conv_b, out);
}